// Round 4
// baseline (516.435 us; speedup 1.0000x reference)
//
#include <hip/hip_runtime.h>
#include <math.h>

#define BATCH 16
#define CIN 4
#define LEN 300000
#define KW 11
#define LC (LEN - KW + 1)   // 299990
#define LCP 300000          // padded row stride for ch workspace
#define LEAK 1e-4f
#define EPS_N 1e-12f

#define TPB 256
#define EPT 4                        // elements per thread (lane-contiguous float4)
#define BPB (TPB * EPT)              // 1024 elements per block
#define NBX ((LC + BPB - 1) / BPB)   // 293 blocks per batch row

// ws layout (tickets zeroed by one small memsetAsync; all else written-before-read):
//   ticketA unsigned[16] stride 64B @ 0       (1024 B)
//   ticketB unsigned[16] stride 64B @ 1024    (1024 B)
//   absP    double[16*NBX]          @ 2048    (37504 B)
//   maxP    float [16*NBX]          @ 40960   (18752 B)
//   stats   float [32]              @ 61440   {denom,max} per b
//   sP      double[16*NBX*3]        @ 65536   (112512 B)
//   ch      float [BATCH*LCP]       @ 262144  (19.2 MB)

__global__ __launch_bounds__(256) void conv_stats(
    const float* __restrict__ data, const float* __restrict__ W,
    const float* __restrict__ bias, const int* __restrict__ aidx,
    float* __restrict__ ch, double* __restrict__ absP, float* __restrict__ maxP,
    float* __restrict__ stats, unsigned* __restrict__ ticket)
{
    const int b = blockIdx.y, j = blockIdx.x, tid = threadIdx.x;
    const int a = aidx[0];              // uniform -> scalar load

    float w[CIN * KW];                  // uniform indices -> SGPRs
#pragma unroll
    for (int k = 0; k < CIN * KW; ++k) w[k] = W[a * CIN * KW + k];
    const float sb = bias[a];

    const float* dbase = data + (size_t)b * (CIN * (size_t)LEN);
    float* chrow = ch + (size_t)b * LCP;
    const int o = (j * TPB + tid) * EPT;

    float aabs = 0.0f, amax = -INFINITY;

    if (o + 16 <= LEN && o + EPT <= LC) {   // o <= 299984: loads and outputs in-bounds
        float acc0 = sb, acc1 = sb, acc2 = sb, acc3 = sb;
#pragma unroll
        for (int c = 0; c < CIN; ++c) {
            const float* src = dbase + (size_t)c * LEN + o;
            const float4 v0 = *(const float4*)(src);
            const float4 v1 = *(const float4*)(src + 4);
            const float4 v2 = *(const float4*)(src + 8);
            const float4 v3 = *(const float4*)(src + 12);
            float x[16] = { v0.x, v0.y, v0.z, v0.w,  v1.x, v1.y, v1.z, v1.w,
                            v2.x, v2.y, v2.z, v2.w,  v3.x, v3.y, v3.z, v3.w };
#pragma unroll
            for (int k = 0; k < KW; ++k) {
                const float wv = w[c * KW + k];
                acc0 = fmaf(x[k],     wv, acc0);
                acc1 = fmaf(x[k + 1], wv, acc1);
                acc2 = fmaf(x[k + 2], wv, acc2);
                acc3 = fmaf(x[k + 3], wv, acc3);
            }
        }
        float4 y;
        y.x = acc0 > 0.0f ? acc0 : LEAK * acc0;
        y.y = acc1 > 0.0f ? acc1 : LEAK * acc1;
        y.z = acc2 > 0.0f ? acc2 : LEAK * acc2;
        y.w = acc3 > 0.0f ? acc3 : LEAK * acc3;
        *(float4*)(chrow + o) = y;
        aabs = (fabsf(y.x) + fabsf(y.y)) + (fabsf(y.z) + fabsf(y.w));
        amax = fmaxf(fmaxf(y.x, y.y), fmaxf(y.z, y.w));
    } else {
        for (int l = o; l < min(o + EPT, LC); ++l) {
            float accv = sb;
#pragma unroll
            for (int c = 0; c < CIN; ++c)
#pragma unroll
                for (int k = 0; k < KW; ++k)
                    accv = fmaf(dbase[(size_t)c * LEN + l + k], w[c * KW + k], accv);
            const float y = accv > 0.0f ? accv : LEAK * accv;
            chrow[l] = y;
            aabs += fabsf(y);
            amax = fmaxf(amax, y);
        }
    }

    // block reduction (no atomics on data), per-row ticket for final reduce
#pragma unroll
    for (int off = 32; off; off >>= 1) {
        aabs += __shfl_down(aabs, off);
        amax = fmaxf(amax, __shfl_down(amax, off));
    }
    __shared__ float ra[4], rm[4];
    __shared__ bool last;
    const int wv = tid >> 6;
    if ((tid & 63) == 0) { ra[wv] = aabs; rm[wv] = amax; }
    __syncthreads();
    if (tid == 0) {
        absP[b * NBX + j] = (double)((ra[0] + ra[1]) + (ra[2] + ra[3]));
        maxP[b * NBX + j] = fmaxf(fmaxf(rm[0], rm[1]), fmaxf(rm[2], rm[3]));
        __threadfence();
        last = (atomicAdd(&ticket[b * 16], 1u) == NBX - 1);  // 16 u32 = 64B stride
    }
    __syncthreads();
    if (last) {
        __threadfence();
        const int lane = tid & 63;
        double s = 0.0; float m = -INFINITY;
        if (tid < 64) {                 // one wave reduces this row's 293 partials
            for (int i = lane; i < NBX; i += 64) {
                s += absP[b * NBX + i];
                m = fmaxf(m, maxP[b * NBX + i]);
            }
#pragma unroll
            for (int off = 32; off; off >>= 1) {
                s += __shfl_down(s, off);
                m = fmaxf(m, __shfl_down(m, off));
            }
            if (lane == 0) {
                stats[2 * b]     = fmaxf((float)s, EPS_N);
                stats[2 * b + 1] = m;
            }
        }
    }
}

__global__ __launch_bounds__(256) void softmax_pass(
    const float* __restrict__ ch, const float* __restrict__ stats,
    float* __restrict__ chan_out, double* __restrict__ sP,
    float* __restrict__ out, unsigned* __restrict__ ticket)
{
    const int b = blockIdx.y, j = blockIdx.x, tid = threadIdx.x;
    const float inv = 1.0f / stats[2 * b];
    const float mx  = stats[2 * b + 1] * inv;

    const float* src = ch + (size_t)b * LCP;
    float* dst = chan_out + (size_t)b * LC;   // base: (32 + b*299990) % 4 == (2b)&3
    const int o = (j * TPB + tid) * EPT;

    double te = 0.0, t1 = 0.0, t2 = 0.0;

    if (o + EPT <= LC) {
        const float4 v = *(const float4*)(src + o);
        const float c0 = v.x * inv, c1 = v.y * inv, c2 = v.z * inv, c3 = v.w * inv;
        if ((b & 1) == 0) {
            *(float4*)(dst + o) = make_float4(c0, c1, c2, c3);
        } else {                        // row base only 8B-aligned
            *(float2*)(dst + o)     = make_float2(c0, c1);
            *(float2*)(dst + o + 2) = make_float2(c2, c3);
        }
        const float e0 = expf(c0 - mx), e1 = expf(c1 - mx);
        const float e2 = expf(c2 - mx), e3 = expf(c3 - mx);
        const float se  = (e0 + e1) + (e2 + e3);
        const float su  = e1 + 2.0f * e2 + 3.0f * e3;
        const float suu = e1 + 4.0f * e2 + 9.0f * e3;
        const double od = (double)o;
        te = (double)se;
        t1 = od * (double)se + (double)su;
        t2 = od * od * (double)se + 2.0 * od * (double)su + (double)suu;
    } else {
        for (int l = o; l < LC; ++l) {
            const float c = src[l] * inv;
            dst[l] = c;
            const float e = expf(c - mx);
            const double xd = (double)l;
            te += (double)e;
            t1 += (double)e * xd;
            t2 += (double)e * xd * xd;
        }
    }

#pragma unroll
    for (int off = 32; off; off >>= 1) {
        te += __shfl_down(te, off);
        t1 += __shfl_down(t1, off);
        t2 += __shfl_down(t2, off);
    }
    __shared__ double we[4], w1[4], w2[4];
    __shared__ bool last;
    const int wv = tid >> 6;
    if ((tid & 63) == 0) { we[wv] = te; w1[wv] = t1; w2[wv] = t2; }
    __syncthreads();
    if (tid == 0) {
        double* p = sP + (size_t)(b * NBX + j) * 3;
        p[0] = (we[0] + we[1]) + (we[2] + we[3]);
        p[1] = (w1[0] + w1[1]) + (w1[2] + w1[3]);
        p[2] = (w2[0] + w2[1]) + (w2[2] + w2[3]);
        __threadfence();
        last = (atomicAdd(&ticket[b * 16], 1u) == NBX - 1);
    }
    __syncthreads();
    if (last && tid < 64) {
        __threadfence();
        const int lane = tid & 63;
        double e = 0.0, m1 = 0.0, m2 = 0.0;
        for (int i = lane; i < NBX; i += 64) {
            const double* p = sP + (size_t)(b * NBX + i) * 3;
            e += p[0]; m1 += p[1]; m2 += p[2];
        }
#pragma unroll
        for (int off = 32; off; off >>= 1) {
            e  += __shfl_down(e, off);
            m1 += __shfl_down(m1, off);
            m2 += __shfl_down(m2, off);
        }
        if (lane == 0) {
            const double mean = m1 / e;
            const double var  = m2 / e - mean * mean;

            const double n   = (double)LC;
            const double nm1 = n - 1.0;
            const double S1p = 0.5 * n * nm1;
            const double S2p = nm1 * n * (2.0 * n - 1.0) / 6.0;
            const double S3p = S1p * S1p;
            const double S4p = S2p * (3.0 * n * n - 3.0 * n - 1.0) / 5.0;

            const double mu  = mean;
            const double mu2 = mu * mu;
            const double P3 = S3p - 3.0 * mu * S2p + 3.0 * mu2 * S1p - n * mu * mu2;
            const double P4 = S4p - 4.0 * mu * S3p + 6.0 * mu2 * S2p
                              - 4.0 * mu * mu2 * S1p + n * mu2 * mu2;

            const double sv = sqrt(var);
            out[b]         = (float)(P3 / (n * sv * sv * sv));
            out[BATCH + b] = (float)(P4 / (n * var * var) - 3.0);
        }
    }
}

extern "C" void kernel_launch(void* const* d_in, const int* in_sizes, int n_in,
                              void* d_out, int out_size, void* d_ws, size_t ws_size,
                              hipStream_t stream) {
    const float* data = (const float*)d_in[0];
    const float* W    = (const float*)d_in[1];
    const float* bias = (const float*)d_in[2];
    const int*   aidx = (const int*)d_in[3];
    float* out = (float*)d_out;

    char* ws = (char*)d_ws;
    unsigned* ticketA = (unsigned*)(ws + 0);
    unsigned* ticketB = (unsigned*)(ws + 1024);
    double*   absP    = (double*)  (ws + 2048);
    float*    maxP    = (float*)   (ws + 40960);
    float*    stats   = (float*)   (ws + 61440);
    double*   sP      = (double*)  (ws + 65536);
    float*    ch      = (float*)   (ws + 262144);

    hipMemsetAsync(ws, 0, 2048, stream);

    dim3 grid(NBX, BATCH);
    conv_stats<<<grid, dim3(TPB), 0, stream>>>(data, W, bias, aidx, ch,
                                               absP, maxP, stats, ticketA);
    softmax_pass<<<grid, dim3(TPB), 0, stream>>>(ch, stats, out + 2 * BATCH, sP,
                                                 out, ticketB);
}

// Round 5
// 135.801 us; speedup vs baseline: 3.8029x; 3.8029x over previous
//
#include <hip/hip_runtime.h>
#include <math.h>

#define BATCH 16
#define CIN 4
#define LEN 300000
#define KW 11
#define LC (LEN - KW + 1)   // 299990
#define LCP 300000          // padded row stride for ch workspace
#define LEAK 1e-4f
#define EPS_N 1e-12f

#define TPB 256
#define EPT 4                         // elements per lane per iteration (float4)
#define ITER 4                        // iterations per thread
#define BPB (TPB * EPT * ITER)        // 4096 elements per block
#define NBX ((LC + BPB - 1) / BPB)    // 74 blocks per batch row

// ws layout (no memset; everything written-before-read across kernel boundaries):
//   absP   double[16*NBX]   @ 0       (9472 B)
//   maxP   float [16*NBX]   @ 16384   (4736 B)
//   sP     double[16*NBX*3] @ 32768   (28416 B)
//   ch     float [BATCH*LCP]@ 131072  (19.2 MB)

__global__ __launch_bounds__(256) void conv_stats(
    const float* __restrict__ data, const float* __restrict__ W,
    const float* __restrict__ bias, const int* __restrict__ aidx,
    float* __restrict__ ch, double* __restrict__ absP, float* __restrict__ maxP)
{
    const int b = blockIdx.y, j = blockIdx.x, tid = threadIdx.x;
    const int a = aidx[0];              // uniform -> scalar load

    float w[CIN * KW];                  // uniform indices -> SGPRs
#pragma unroll
    for (int k = 0; k < CIN * KW; ++k) w[k] = W[a * CIN * KW + k];
    const float sb = bias[a];

    const float* dbase = data + (size_t)b * (CIN * (size_t)LEN);
    float* chrow = ch + (size_t)b * LCP;
    const int o0 = j * BPB + tid * EPT;

    float aabs = 0.0f, amax = -INFINITY;

#pragma unroll
    for (int it = 0; it < ITER; ++it) {
        const int o = o0 + it * (TPB * EPT);
        if (o <= LC - EPT && o + 16 <= LEN) {   // fast path, all loads in-bounds
            float acc0 = sb, acc1 = sb, acc2 = sb, acc3 = sb;
#pragma unroll
            for (int c = 0; c < CIN; ++c) {
                const float* src = dbase + (size_t)c * LEN + o;
                const float4 v0 = *(const float4*)(src);
                const float4 v1 = *(const float4*)(src + 4);
                const float4 v2 = *(const float4*)(src + 8);
                const float4 v3 = *(const float4*)(src + 12);
                float x[16] = { v0.x, v0.y, v0.z, v0.w,  v1.x, v1.y, v1.z, v1.w,
                                v2.x, v2.y, v2.z, v2.w,  v3.x, v3.y, v3.z, v3.w };
#pragma unroll
                for (int k = 0; k < KW; ++k) {
                    const float wv = w[c * KW + k];
                    acc0 = fmaf(x[k],     wv, acc0);
                    acc1 = fmaf(x[k + 1], wv, acc1);
                    acc2 = fmaf(x[k + 2], wv, acc2);
                    acc3 = fmaf(x[k + 3], wv, acc3);
                }
            }
            float4 y;
            y.x = acc0 > 0.0f ? acc0 : LEAK * acc0;
            y.y = acc1 > 0.0f ? acc1 : LEAK * acc1;
            y.z = acc2 > 0.0f ? acc2 : LEAK * acc2;
            y.w = acc3 > 0.0f ? acc3 : LEAK * acc3;
            *(float4*)(chrow + o) = y;
            aabs += (fabsf(y.x) + fabsf(y.y)) + (fabsf(y.z) + fabsf(y.w));
            amax = fmaxf(amax, fmaxf(fmaxf(y.x, y.y), fmaxf(y.z, y.w)));
        } else {
            for (int l = o; l < min(o + EPT, LC); ++l) {
                float accv = sb;
#pragma unroll
                for (int c = 0; c < CIN; ++c)
#pragma unroll
                    for (int k = 0; k < KW; ++k)
                        accv = fmaf(dbase[(size_t)c * LEN + l + k], w[c * KW + k], accv);
                const float y = accv > 0.0f ? accv : LEAK * accv;
                chrow[l] = y;
                aabs += fabsf(y);
                amax = fmaxf(amax, y);
            }
        }
    }

    // block reduction -> per-block partials (plain stores, no atomics/fences)
#pragma unroll
    for (int off = 32; off; off >>= 1) {
        aabs += __shfl_down(aabs, off);
        amax = fmaxf(amax, __shfl_down(amax, off));
    }
    __shared__ float ra[4], rm[4];
    const int wv = tid >> 6;
    if ((tid & 63) == 0) { ra[wv] = aabs; rm[wv] = amax; }
    __syncthreads();
    if (tid == 0) {
        absP[b * NBX + j] = (double)((ra[0] + ra[1]) + (ra[2] + ra[3]));
        maxP[b * NBX + j] = fmaxf(fmaxf(rm[0], rm[1]), fmaxf(rm[2], rm[3]));
    }
}

__global__ __launch_bounds__(256) void softmax_pass(
    const float* __restrict__ ch, const double* __restrict__ absP,
    const float* __restrict__ maxP, float* __restrict__ chan_out,
    double* __restrict__ sP)
{
    const int b = blockIdx.y, j = blockIdx.x, tid = threadIdx.x;

    // every block redundantly reduces its row's 74 partials (cheap, no fence needed:
    // kernel boundary made conv_stats' writes visible)
    __shared__ float sstat[2];
    if (tid < 64) {
        double s = 0.0; float m = -INFINITY;
        for (int i = tid; i < NBX; i += 64) {
            s += absP[b * NBX + i];
            m = fmaxf(m, maxP[b * NBX + i]);
        }
#pragma unroll
        for (int off = 32; off; off >>= 1) {
            s += __shfl_down(s, off);
            m = fmaxf(m, __shfl_down(m, off));
        }
        if (tid == 0) {
            sstat[0] = fmaxf((float)s, EPS_N);
            sstat[1] = m;
        }
    }
    __syncthreads();
    const float inv = 1.0f / sstat[0];
    const float mx  = sstat[1] * inv;

    const float* src = ch + (size_t)b * LCP;
    float* dst = chan_out + (size_t)b * LC;   // base: (32 + b*299990) % 4 == (2b)&3
    const int o0 = j * BPB + tid * EPT;

    double te = 0.0, t1 = 0.0, t2 = 0.0;

#pragma unroll
    for (int it = 0; it < ITER; ++it) {
        const int o = o0 + it * (TPB * EPT);
        if (o <= LC - EPT) {
            const float4 v = *(const float4*)(src + o);
            const float c0 = v.x * inv, c1 = v.y * inv, c2 = v.z * inv, c3 = v.w * inv;
            if ((b & 1) == 0) {
                *(float4*)(dst + o) = make_float4(c0, c1, c2, c3);
            } else {                    // row base only 8B-aligned
                *(float2*)(dst + o)     = make_float2(c0, c1);
                *(float2*)(dst + o + 2) = make_float2(c2, c3);
            }
            const float e0 = expf(c0 - mx), e1 = expf(c1 - mx);
            const float e2 = expf(c2 - mx), e3 = expf(c3 - mx);
            const float se  = (e0 + e1) + (e2 + e3);
            const float su  = e1 + 2.0f * e2 + 3.0f * e3;
            const float suu = e1 + 4.0f * e2 + 9.0f * e3;
            const double od = (double)o;
            te += (double)se;
            t1 += od * (double)se + (double)su;
            t2 += od * od * (double)se + 2.0 * od * (double)su + (double)suu;
        } else {
            for (int l = o; l < LC; ++l) {
                const float c = src[l] * inv;
                dst[l] = c;
                const float e = expf(c - mx);
                const double xd = (double)l;
                te += (double)e;
                t1 += (double)e * xd;
                t2 += (double)e * xd * xd;
            }
        }
    }

#pragma unroll
    for (int off = 32; off; off >>= 1) {
        te += __shfl_down(te, off);
        t1 += __shfl_down(t1, off);
        t2 += __shfl_down(t2, off);
    }
    __shared__ double we[4], w1[4], w2[4];
    const int wv = tid >> 6;
    if ((tid & 63) == 0) { we[wv] = te; w1[wv] = t1; w2[wv] = t2; }
    __syncthreads();
    if (tid == 0) {
        double* p = sP + (size_t)(b * NBX + j) * 3;
        p[0] = (we[0] + we[1]) + (we[2] + we[3]);
        p[1] = (w1[0] + w1[1]) + (w1[2] + w1[3]);
        p[2] = (w2[0] + w2[1]) + (w2[2] + w2[3]);
    }
}

__global__ void finalize(const double* __restrict__ sP, float* __restrict__ out)
{
    const int b = blockIdx.x, t = threadIdx.x;
    double te = 0.0, t1 = 0.0, t2 = 0.0;
    for (int i = t; i < NBX; i += 64) {
        const double* p = sP + (size_t)(b * NBX + i) * 3;
        te += p[0]; t1 += p[1]; t2 += p[2];
    }
#pragma unroll
    for (int off = 32; off; off >>= 1) {
        te += __shfl_down(te, off);
        t1 += __shfl_down(t1, off);
        t2 += __shfl_down(t2, off);
    }
    if (t == 0) {
        const double E    = te;
        const double mean = t1 / E;
        const double var  = t2 / E - mean * mean;

        const double n   = (double)LC;
        const double nm1 = n - 1.0;
        const double S1p = 0.5 * n * nm1;
        const double S2p = nm1 * n * (2.0 * n - 1.0) / 6.0;
        const double S3p = S1p * S1p;
        const double S4p = S2p * (3.0 * n * n - 3.0 * n - 1.0) / 5.0;

        const double mu  = mean;
        const double mu2 = mu * mu;
        const double P3 = S3p - 3.0 * mu * S2p + 3.0 * mu2 * S1p - n * mu * mu2;
        const double P4 = S4p - 4.0 * mu * S3p + 6.0 * mu2 * S2p
                          - 4.0 * mu * mu2 * S1p + n * mu2 * mu2;

        const double sv = sqrt(var);
        out[b]         = (float)(P3 / (n * sv * sv * sv));
        out[BATCH + b] = (float)(P4 / (n * var * var) - 3.0);
    }
}

extern "C" void kernel_launch(void* const* d_in, const int* in_sizes, int n_in,
                              void* d_out, int out_size, void* d_ws, size_t ws_size,
                              hipStream_t stream) {
    const float* data = (const float*)d_in[0];
    const float* W    = (const float*)d_in[1];
    const float* bias = (const float*)d_in[2];
    const int*   aidx = (const int*)d_in[3];
    float* out = (float*)d_out;

    char* ws = (char*)d_ws;
    double* absP = (double*)(ws + 0);
    float*  maxP = (float*) (ws + 16384);
    double* sP   = (double*)(ws + 32768);
    float*  ch   = (float*) (ws + 131072);

    dim3 grid(NBX, BATCH);
    conv_stats<<<grid, dim3(TPB), 0, stream>>>(data, W, bias, aidx, ch, absP, maxP);
    softmax_pass<<<grid, dim3(TPB), 0, stream>>>(ch, absP, maxP, out + 2 * BATCH, sP);
    finalize<<<dim3(BATCH), dim3(64), 0, stream>>>(sP, out);
}

// Round 7
// 133.112 us; speedup vs baseline: 3.8797x; 1.0202x over previous
//
#include <hip/hip_runtime.h>
#include <hip/hip_cooperative_groups.h>
#include <math.h>

namespace cg = cooperative_groups;

#define BATCH 16
#define CIN 4
#define LEN 300000
#define KW 11
#define LC (LEN - KW + 1)   // 299990
#define LCP 300000          // padded ch row stride (fallback path only)
#define LEAK 1e-4f
#define EPS_N 1e-12f

#define TPB 256
#define EPT 4
#define NBX 64                        // blocks per batch row
#define NBLK (NBX * BATCH)            // 1024 total blocks
#define CHUNK 4688                    // ceil(LC/NBX), multiple of 4
#define ITER 5                        // ceil(CHUNK / (TPB*EPT))

// ws layout (written-before-read; harness 0xAA poison is fine):
//   absP double[NBLK]    @ 0      (8192 B)
//   maxP float [NBLK]    @ 8192   (4096 B)
//   sP   double[NBLK*3]  @ 16384  (24576 B)
//   ch   float[BATCH*LCP]@ 65536  (19.2 MB, fallback only)

// ---------------------------------------------------------------------------
// shared device helpers
// ---------------------------------------------------------------------------
__device__ inline void conv_iter_fast(const float* __restrict__ src,
                                      const float* w, float sb, float* yo)
{
    float acc0 = sb, acc1 = sb, acc2 = sb, acc3 = sb;
#pragma unroll
    for (int c = 0; c < CIN; ++c) {
        const float* s = src + (size_t)c * LEN;
        const float4 v0 = *(const float4*)(s);
        const float4 v1 = *(const float4*)(s + 4);
        const float4 v2 = *(const float4*)(s + 8);
        const float4 v3 = *(const float4*)(s + 12);
        float x[16] = { v0.x, v0.y, v0.z, v0.w,  v1.x, v1.y, v1.z, v1.w,
                        v2.x, v2.y, v2.z, v2.w,  v3.x, v3.y, v3.z, v3.w };
#pragma unroll
        for (int k = 0; k < KW; ++k) {
            const float wv = w[c * KW + k];
            acc0 = fmaf(x[k],     wv, acc0);
            acc1 = fmaf(x[k + 1], wv, acc1);
            acc2 = fmaf(x[k + 2], wv, acc2);
            acc3 = fmaf(x[k + 3], wv, acc3);
        }
    }
    yo[0] = acc0 > 0.0f ? acc0 : LEAK * acc0;
    yo[1] = acc1 > 0.0f ? acc1 : LEAK * acc1;
    yo[2] = acc2 > 0.0f ? acc2 : LEAK * acc2;
    yo[3] = acc3 > 0.0f ? acc3 : LEAK * acc3;
}

__device__ inline float conv_one(const float* __restrict__ dbase, int l,
                                 const float* w, float sb)
{
    float acc = sb;
#pragma unroll
    for (int c = 0; c < CIN; ++c)
#pragma unroll
        for (int k = 0; k < KW; ++k)
            acc = fmaf(dbase[(size_t)c * LEN + l + k], w[c * KW + k], acc);
    return acc > 0.0f ? acc : LEAK * acc;
}

__device__ inline void finalize_row(double e, double m1, double m2,
                                    float* __restrict__ out, int b)
{
    const double mean = m1 / e;
    const double var  = m2 / e - mean * mean;

    const double n   = (double)LC;
    const double nm1 = n - 1.0;
    const double S1p = 0.5 * n * nm1;
    const double S2p = nm1 * n * (2.0 * n - 1.0) / 6.0;
    const double S3p = S1p * S1p;
    const double S4p = S2p * (3.0 * n * n - 3.0 * n - 1.0) / 5.0;

    const double mu  = mean;
    const double mu2 = mu * mu;
    const double P3 = S3p - 3.0 * mu * S2p + 3.0 * mu2 * S1p - n * mu * mu2;
    const double P4 = S4p - 4.0 * mu * S3p + 6.0 * mu2 * S2p
                      - 4.0 * mu * mu2 * S1p + n * mu2 * mu2;

    const double sv = sqrt(var);
    out[b]         = (float)(P3 / (n * sv * sv * sv));
    out[BATCH + b] = (float)(P4 / (n * var * var) - 3.0);
}

// ---------------------------------------------------------------------------
// cooperative fused kernel
// ---------------------------------------------------------------------------
__global__ __launch_bounds__(256, 4) void fused(
    const float* __restrict__ data, const float* __restrict__ W,
    const float* __restrict__ bias, const int* __restrict__ aidx,
    float* __restrict__ out,
    double* __restrict__ absP, float* __restrict__ maxP, double* __restrict__ sP)
{
    cg::grid_group grid = cg::this_grid();

    const int b = blockIdx.y, j = blockIdx.x, tid = threadIdx.x;
    const int a = aidx[0];

    float w[CIN * KW];
#pragma unroll
    for (int k = 0; k < CIN * KW; ++k) w[k] = W[a * CIN * KW + k];
    const float sb = bias[a];

    const float* dbase = data + (size_t)b * (CIN * (size_t)LEN);
    const int cstart = j * CHUNK;
    const int cend   = min(cstart + CHUNK, LC);

    // ---------------- phase 1: conv + leaky, results held in registers --------
    float y[ITER][EPT];
    float aabs = 0.0f, amax = -INFINITY;

#pragma unroll
    for (int it = 0; it < ITER; ++it) {
        const int o = cstart + it * (TPB * EPT) + tid * EPT;
        if (o + EPT <= cend && o + 16 <= LEN) {
            conv_iter_fast(dbase + o, w, sb, y[it]);
            aabs += (fabsf(y[it][0]) + fabsf(y[it][1])) +
                    (fabsf(y[it][2]) + fabsf(y[it][3]));
            amax = fmaxf(amax, fmaxf(fmaxf(y[it][0], y[it][1]),
                                     fmaxf(y[it][2], y[it][3])));
        } else {
#pragma unroll
            for (int u = 0; u < EPT; ++u) {
                const int l = o + u;
                if (l < cend) {
                    const float v = conv_one(dbase, l, w, sb);
                    y[it][u] = v;
                    aabs += fabsf(v);
                    amax = fmaxf(amax, v);
                }
            }
        }
    }

#pragma unroll
    for (int off = 32; off; off >>= 1) {
        aabs += __shfl_down(aabs, off);
        amax = fmaxf(amax, __shfl_down(amax, off));
    }
    __shared__ float ra[4], rm[4];
    const int wv = tid >> 6;
    if ((tid & 63) == 0) { ra[wv] = aabs; rm[wv] = amax; }
    __syncthreads();
    if (tid == 0) {
        absP[b * NBX + j] = (double)((ra[0] + ra[1]) + (ra[2] + ra[3]));
        maxP[b * NBX + j] = fmaxf(fmaxf(rm[0], rm[1]), fmaxf(rm[2], rm[3]));
    }

    grid.sync();   // ~12B dirty/block: cheap

    // ---------------- phase 2: per-block stats reduce + softmax ---------------
    __shared__ float sstat[2];
    if (tid < 64) {
        double s = absP[b * NBX + tid];          // NBX == 64: one partial/lane
        float  m = maxP[b * NBX + tid];
#pragma unroll
        for (int off = 32; off; off >>= 1) {
            s += __shfl_down(s, off);
            m = fmaxf(m, __shfl_down(m, off));
        }
        if (tid == 0) {
            sstat[0] = fmaxf((float)s, EPS_N);
            sstat[1] = m;
        }
    }
    __syncthreads();
    const float inv = 1.0f / sstat[0];
    const float mx  = sstat[1] * inv;

    float* dst = out + 2 * BATCH + (size_t)b * LC;  // elem base mod4 = (2b)&3

    double te = 0.0, t1 = 0.0, t2 = 0.0;

#pragma unroll
    for (int it = 0; it < ITER; ++it) {
        const int o = cstart + it * (TPB * EPT) + tid * EPT;
        if (o + EPT <= cend && o + 16 <= LEN) {   // must match phase-1 condition
            const float c0 = y[it][0] * inv, c1 = y[it][1] * inv;
            const float c2 = y[it][2] * inv, c3 = y[it][3] * inv;
            if ((b & 1) == 0) {
                *(float4*)(dst + o) = make_float4(c0, c1, c2, c3);
            } else {
                *(float2*)(dst + o)     = make_float2(c0, c1);
                *(float2*)(dst + o + 2) = make_float2(c2, c3);
            }
            const float e0 = expf(c0 - mx), e1 = expf(c1 - mx);
            const float e2 = expf(c2 - mx), e3 = expf(c3 - mx);
            const float se  = (e0 + e1) + (e2 + e3);
            const float su  = e1 + 2.0f * e2 + 3.0f * e3;
            const float suu = e1 + 4.0f * e2 + 9.0f * e3;
            const double od = (double)o;
            te += (double)se;
            t1 += od * (double)se + (double)su;
            t2 += od * od * (double)se + 2.0 * od * (double)su + (double)suu;
        } else {
#pragma unroll
            for (int u = 0; u < EPT; ++u) {
                const int l = o + u;
                if (l < cend) {
                    const float c = y[it][u] * inv;
                    dst[l] = c;
                    const float e = expf(c - mx);
                    const double xd = (double)l;
                    te += (double)e;
                    t1 += (double)e * xd;
                    t2 += (double)e * xd * xd;
                }
            }
        }
    }

#pragma unroll
    for (int off = 32; off; off >>= 1) {
        te += __shfl_down(te, off);
        t1 += __shfl_down(t1, off);
        t2 += __shfl_down(t2, off);
    }
    __shared__ double we[4], w1[4], w2[4];
    if ((tid & 63) == 0) { we[wv] = te; w1[wv] = t1; w2[wv] = t2; }
    __syncthreads();
    if (tid == 0) {
        double* p = sP + (size_t)(b * NBX + j) * 3;
        p[0] = (we[0] + we[1]) + (we[2] + we[3]);
        p[1] = (w1[0] + w1[1]) + (w1[2] + w1[3]);
        p[2] = (w2[0] + w2[1]) + (w2[2] + w2[3]);
    }

    grid.sync();

    // ---------------- phase 3: 16 blocks finalize -----------------------------
    if (j == 0 && tid < 64) {
        const double* p = sP + (size_t)(b * NBX + tid) * 3;
        double e = p[0], m1 = p[1], m2 = p[2];
#pragma unroll
        for (int off = 32; off; off >>= 1) {
            e  += __shfl_down(e, off);
            m1 += __shfl_down(m1, off);
            m2 += __shfl_down(m2, off);
        }
        if (tid == 0) finalize_row(e, m1, m2, out, b);
    }
}

// ---------------------------------------------------------------------------
// fallback path (R4 structure, proven correct at 136 us)
// ---------------------------------------------------------------------------
__global__ __launch_bounds__(256) void conv_stats_fb(
    const float* __restrict__ data, const float* __restrict__ W,
    const float* __restrict__ bias, const int* __restrict__ aidx,
    float* __restrict__ ch, double* __restrict__ absP, float* __restrict__ maxP)
{
    const int b = blockIdx.y, j = blockIdx.x, tid = threadIdx.x;
    const int a = aidx[0];
    float w[CIN * KW];
#pragma unroll
    for (int k = 0; k < CIN * KW; ++k) w[k] = W[a * CIN * KW + k];
    const float sb = bias[a];

    const float* dbase = data + (size_t)b * (CIN * (size_t)LEN);
    float* chrow = ch + (size_t)b * LCP;
    const int cstart = j * CHUNK;
    const int cend   = min(cstart + CHUNK, LC);

    float aabs = 0.0f, amax = -INFINITY;
#pragma unroll
    for (int it = 0; it < ITER; ++it) {
        const int o = cstart + it * (TPB * EPT) + tid * EPT;
        if (o + EPT <= cend && o + 16 <= LEN) {
            float yv[EPT];
            conv_iter_fast(dbase + o, w, sb, yv);
            *(float4*)(chrow + o) = make_float4(yv[0], yv[1], yv[2], yv[3]);
            aabs += (fabsf(yv[0]) + fabsf(yv[1])) + (fabsf(yv[2]) + fabsf(yv[3]));
            amax = fmaxf(amax, fmaxf(fmaxf(yv[0], yv[1]), fmaxf(yv[2], yv[3])));
        } else {
            for (int l = o; l < min(o + EPT, cend); ++l) {
                const float v = conv_one(dbase, l, w, sb);
                chrow[l] = v;
                aabs += fabsf(v);
                amax = fmaxf(amax, v);
            }
        }
    }

#pragma unroll
    for (int off = 32; off; off >>= 1) {
        aabs += __shfl_down(aabs, off);
        amax = fmaxf(amax, __shfl_down(amax, off));
    }
    __shared__ float ra[4], rm[4];
    const int wv = tid >> 6;
    if ((tid & 63) == 0) { ra[wv] = aabs; rm[wv] = amax; }
    __syncthreads();
    if (tid == 0) {
        absP[b * NBX + j] = (double)((ra[0] + ra[1]) + (ra[2] + ra[3]));
        maxP[b * NBX + j] = fmaxf(fmaxf(rm[0], rm[1]), fmaxf(rm[2], rm[3]));
    }
}

__global__ __launch_bounds__(256) void softmax_fb(
    const float* __restrict__ ch, const double* __restrict__ absP,
    const float* __restrict__ maxP, float* __restrict__ chan_out,
    double* __restrict__ sP)
{
    const int b = blockIdx.y, j = blockIdx.x, tid = threadIdx.x;

    __shared__ float sstat[2];
    if (tid < 64) {
        double s = absP[b * NBX + tid];
        float  m = maxP[b * NBX + tid];
#pragma unroll
        for (int off = 32; off; off >>= 1) {
            s += __shfl_down(s, off);
            m = fmaxf(m, __shfl_down(m, off));
        }
        if (tid == 0) { sstat[0] = fmaxf((float)s, EPS_N); sstat[1] = m; }
    }
    __syncthreads();
    const float inv = 1.0f / sstat[0];
    const float mx  = sstat[1] * inv;

    const float* src = ch + (size_t)b * LCP;
    float* dst = chan_out + (size_t)b * LC;
    const int cstart = j * CHUNK;
    const int cend   = min(cstart + CHUNK, LC);

    double te = 0.0, t1 = 0.0, t2 = 0.0;
#pragma unroll
    for (int it = 0; it < ITER; ++it) {
        const int o = cstart + it * (TPB * EPT) + tid * EPT;
        if (o + EPT <= cend) {
            const float4 v = *(const float4*)(src + o);
            const float c0 = v.x * inv, c1 = v.y * inv, c2 = v.z * inv, c3 = v.w * inv;
            if ((b & 1) == 0) {
                *(float4*)(dst + o) = make_float4(c0, c1, c2, c3);
            } else {
                *(float2*)(dst + o)     = make_float2(c0, c1);
                *(float2*)(dst + o + 2) = make_float2(c2, c3);
            }
            const float e0 = expf(c0 - mx), e1 = expf(c1 - mx);
            const float e2 = expf(c2 - mx), e3 = expf(c3 - mx);
            const float se  = (e0 + e1) + (e2 + e3);
            const float su  = e1 + 2.0f * e2 + 3.0f * e3;
            const float suu = e1 + 4.0f * e2 + 9.0f * e3;
            const double od = (double)o;
            te += (double)se;
            t1 += od * (double)se + (double)su;
            t2 += od * od * (double)se + 2.0 * od * (double)su + (double)suu;
        } else {
            for (int l = o; l < cend; ++l) {
                const float c = src[l] * inv;
                dst[l] = c;
                const float e = expf(c - mx);
                const double xd = (double)l;
                te += (double)e;
                t1 += (double)e * xd;
                t2 += (double)e * xd * xd;
            }
        }
    }

#pragma unroll
    for (int off = 32; off; off >>= 1) {
        te += __shfl_down(te, off);
        t1 += __shfl_down(t1, off);
        t2 += __shfl_down(t2, off);
    }
    __shared__ double we[4], w1[4], w2[4];
    const int wv = tid >> 6;
    if ((tid & 63) == 0) { we[wv] = te; w1[wv] = t1; w2[wv] = t2; }
    __syncthreads();
    if (tid == 0) {
        double* p = sP + (size_t)(b * NBX + j) * 3;
        p[0] = (we[0] + we[1]) + (we[2] + we[3]);
        p[1] = (w1[0] + w1[1]) + (w1[2] + w1[3]);
        p[2] = (w2[0] + w2[1]) + (w2[2] + w2[3]);
    }
}

__global__ void finalize_fb(const double* __restrict__ sP, float* __restrict__ out)
{
    const int b = blockIdx.x, t = threadIdx.x;
    const double* p = sP + (size_t)(b * NBX + t) * 3;
    double te = p[0], t1 = p[1], t2 = p[2];
#pragma unroll
    for (int off = 32; off; off >>= 1) {
        te += __shfl_down(te, off);
        t1 += __shfl_down(t1, off);
        t2 += __shfl_down(t2, off);
    }
    if (t == 0) finalize_row(te, t1, t2, out, b);
}

// ---------------------------------------------------------------------------
extern "C" void kernel_launch(void* const* d_in, const int* in_sizes, int n_in,
                              void* d_out, int out_size, void* d_ws, size_t ws_size,
                              hipStream_t stream) {
    const float* data = (const float*)d_in[0];
    const float* W    = (const float*)d_in[1];
    const float* bias = (const float*)d_in[2];
    const int*   aidx = (const int*)d_in[3];
    float* out = (float*)d_out;

    char* ws = (char*)d_ws;
    double* absP = (double*)(ws + 0);
    float*  maxP = (float*) (ws + 8192);
    double* sP   = (double*)(ws + 16384);
    float*  ch   = (float*) (ws + 65536);

    // host-side, deterministic, graph-capture-safe occupancy check
    int bpc = 0;
    hipError_t oe = hipOccupancyMaxActiveBlocksPerMultiprocessor(
        &bpc, (const void*)fused, TPB, 0);
    const bool coop_ok = (oe == hipSuccess) && (bpc * 256 >= NBLK);

    if (coop_ok) {
        void* args[] = { (void*)&data, (void*)&W, (void*)&bias, (void*)&aidx,
                         (void*)&out, (void*)&absP, (void*)&maxP, (void*)&sP };
        hipLaunchCooperativeKernel((const void*)fused, dim3(NBX, BATCH), dim3(TPB),
                                   args, 0, stream);
    } else {
        dim3 grid(NBX, BATCH);
        conv_stats_fb<<<grid, dim3(TPB), 0, stream>>>(data, W, bias, aidx, ch,
                                                      absP, maxP);
        softmax_fb<<<grid, dim3(TPB), 0, stream>>>(ch, absP, maxP,
                                                   out + 2 * BATCH, sP);
        finalize_fb<<<dim3(BATCH), dim3(64), 0, stream>>>(sP, out);
    }
}